// Round 18
// baseline (323.602 us; speedup 1.0000x reference)
//
#include <hip/hip_runtime.h>
#include <hip/hip_bf16.h>

#define HDIM 4096
#define DHEAD 128
#define NQH 32
#define NKVH 8
#define SEQ 2048
#define QKVN 6144  // fused N = 4096 + 1024 + 1024

typedef __bf16 bf16x8 __attribute__((ext_vector_type(8)));
typedef unsigned short ushort8 __attribute__((ext_vector_type(8)));
typedef float f32x4 __attribute__((ext_vector_type(4)));
typedef float f32x16 __attribute__((ext_vector_type(16)));
typedef unsigned int u32x4 __attribute__((ext_vector_type(4)));

// wait until <= N vector-memory ops outstanding (lgkm/exp not waited)
#define WAIT_VM(N) __builtin_amdgcn_s_waitcnt(0xF70 | (N))

// m201 phase head WITHOUT sched_barrier. Placed before each MFMA cluster.
// NOTE (r17 lesson): all vmcnt gates must stay BEFORE their barrier (vmcnt is
// per-thread; gating after the rendezvous races on cross-thread LDS data).
#define PHASE_HEAD() do {                                     \
        __builtin_amdgcn_s_barrier();                         \
        asm volatile("s_waitcnt lgkmcnt(0)" ::: "memory");    \
    } while (0)

__device__ inline unsigned short f2bf(float f) {
    unsigned u = __float_as_uint(f);
    u += 0x7fffu + ((u >> 16) & 1u);
    return (unsigned short)(u >> 16);
}

__device__ inline float bf2f(unsigned short u) {
    return __uint_as_float(((unsigned)u) << 16);
}

// pack two f32 -> {lo:bf16, hi:bf16} in one u32 (low word = first arg)
__device__ inline unsigned cvtpk(float lo, float hi) {
    unsigned r;
    asm("v_cvt_pk_bf16_f32 %0, %1, %2" : "=v"(r) : "v"(lo), "v"(hi));
    return r;
}

__device__ inline void gload16(const void* g, void* l) {
    __builtin_amdgcn_global_load_lds(
        (const __attribute__((address_space(1))) unsigned int*)g,
        (__attribute__((address_space(3))) unsigned int*)l, 16, 0, 0);
}

// ------- transpose + fp32->bf16 convert: in[K][N] -> out[N][K], 64k x 32n tiles --------
__global__ void transpose_convert(const float* __restrict__ in, unsigned short* __restrict__ out,
                                  int K, int N) {
    __shared__ float tile[64][33];
    const int n0 = blockIdx.x * 32, k0 = blockIdx.y * 64;
    const int tx = threadIdx.x, ty = threadIdx.y;  // 32 x 8
    #pragma unroll
    for (int r = 0; r < 8; r++)
        tile[ty + r * 8][tx] = in[(size_t)(k0 + ty + r * 8) * N + n0 + tx];
    __syncthreads();
    #pragma unroll
    for (int r = 0; r < 4; r++) {
        int n = ty + r * 8;
        unsigned v = (unsigned)f2bf(tile[tx * 2][n]) |
                     ((unsigned)f2bf(tile[tx * 2 + 1][n]) << 16);
        *(unsigned*)&out[(size_t)(n0 + n) * K + k0 + tx * 2] = v;
    }
}

// ---------------- V transpose: bf16 qkv-fused row -> bf16 (NKVH, D, S) ----------------
__global__ void transpose_v(const unsigned short* __restrict__ qkvb,
                            unsigned short* __restrict__ vbt) {
    __shared__ unsigned short tile[32][34];
    const int s0 = blockIdx.x * 32, d0 = blockIdx.y * 32, hv = blockIdx.z;
    const int tx = threadIdx.x, ty = threadIdx.y;  // 32 x 8
    for (int r = 0; r < 32; r += 8)
        tile[ty + r][tx] = qkvb[(size_t)(s0 + ty + r) * QKVN + 5120 + hv * DHEAD + d0 + tx];
    __syncthreads();
    for (int r = 0; r < 32; r += 8)
        vbt[((size_t)hv * DHEAD + d0 + ty + r) * SEQ + s0 + tx] = tile[tx][ty + r];
}

// ---------------- LayerNorm: fp32 (S,H) -> bf16 (S,H) ----------------
__global__ __launch_bounds__(256) void layernorm_kernel(
    const float* __restrict__ hs, const float* __restrict__ w, const float* __restrict__ b,
    unsigned short* __restrict__ xb) {
    const int s = blockIdx.x;
    const float* row = hs + (size_t)s * HDIM;
    const int t = threadIdx.x;
    float vals[16];
    float sum = 0.f, sq = 0.f;
    for (int j = 0; j < 16; j++) {
        float v = row[j * 256 + t];
        vals[j] = v; sum += v; sq += v * v;
    }
    for (int off = 1; off < 64; off <<= 1) {
        sum += __shfl_xor(sum, off);
        sq  += __shfl_xor(sq, off);
    }
    __shared__ float ps[4], pq[4];
    if ((t & 63) == 0) { ps[t >> 6] = sum; pq[t >> 6] = sq; }
    __syncthreads();
    sum = ps[0] + ps[1] + ps[2] + ps[3];
    sq  = pq[0] + pq[1] + pq[2] + pq[3];
    const float mu = sum * (1.0f / HDIM);
    const float var = sq * (1.0f / HDIM) - mu * mu;
    const float rs = rsqrtf(var + 1e-5f);
    for (int j = 0; j < 16; j++) {
        int i = j * 256 + t;
        xb[(size_t)s * HDIM + i] = f2bf((vals[j] - mu) * rs * w[i] + b[i]);
    }
}

// ------- gemm11 (QKV): BM=256, BN=192, BK=64 -> grid 8 x 32 = 256 blocks (full chip) ---
// = r16 ledger/gates EXACTLY + PHASE_HEAD before each MFMA cluster (no sched_barrier).
//   ph0 gate WAIT_VM(2)->barrier forces A-kh1(kt); ph1 gate WAIT_VM(2)->barrier forces
//   A-kh0+B of kt+1; A-kh1(kt+1) stays in flight.
__global__ __launch_bounds__(512, 1) void gemm11(
    const unsigned short* __restrict__ A, const unsigned short* __restrict__ Bt,
    void* __restrict__ Cout, int N, int lda, int Keff, int nbx, int cBf16) {
    __shared__ __align__(16) unsigned short Abuf[2 * 2 * 256 * 32];  // 64 KB
    __shared__ __align__(16) unsigned short Bbuf[2 * 192 * 64];      // 48 KB

    const int inner = blockIdx.x;
    const int cbx = nbx >> 3;
    const int xcd = inner & 7, k = inner >> 3;
    const int bx = xcd * cbx + (k % cbx);
    const int by = k / cbx;
    const int row0 = by * 256, col0 = bx * 192;

    const int t = threadIdx.x, lane = t & 63, w = t >> 6;
    const int wr = w >> 2, wc = w & 3;          // 2M x 4N wave grid
    const int r16 = lane & 15, kq = lane >> 4;

    const int srowA = t >> 2;
    const int scswA = (t & 3) ^ ((srowA >> 1) & 3);
    const unsigned short* aS = A + (size_t)(row0 + srowA) * lda + scswA * 8;
    const int srowB = t >> 3;
    const int scswB = (t & 7) ^ (srowB & 7);
    const unsigned short* bS = Bt + (size_t)(col0 + srowB) * lda + scswB * 8;
    const size_t a128 = 128 * (size_t)lda;
    const size_t b64 = 64 * (size_t)lda;
    const int wdst = w * 512;

    const int NT = Keff / 64;

#define SA11(bufi, kh, kt) {                                                        \
        const unsigned short* _g = aS + (size_t)(kt) * 64 + (kh) * 32;              \
        gload16(_g,        &Abuf[(bufi) * 16384 + (kh) * 8192 + wdst]);             \
        gload16(_g + a128, &Abuf[(bufi) * 16384 + (kh) * 8192 + 4096 + wdst]); }
#define SB11(bufi, kt) {                                                            \
        const unsigned short* _g = bS + (size_t)(kt) * 64;                          \
        gload16(_g,            &Bbuf[(bufi) * 12288 + wdst]);                       \
        gload16(_g + b64,      &Bbuf[(bufi) * 12288 + 4096 + wdst]);                \
        gload16(_g + 2 * b64,  &Bbuf[(bufi) * 12288 + 8192 + wdst]); }
#define RA11(dst, bufi, kh) { _Pragma("unroll") for (int i = 0; i < 8; i++) {       \
        int ar = wr * 128 + i * 16 + r16;                                           \
        dst[i] = *(const bf16x8*)&Abuf[(bufi) * 16384 + (kh) * 8192 + ar * 32 +     \
                 (kq ^ ((ar >> 1) & 3)) * 8]; } }
#define RB11(dst, bufi, kh) { _Pragma("unroll") for (int j = 0; j < 3; j++) {       \
        int br = wc * 48 + j * 16 + r16;                                            \
        dst[j] = *(const bf16x8*)&Bbuf[(bufi) * 12288 + br * 64 +                   \
                 ((((kh) * 4) + kq) ^ (br & 7)) * 8]; } }
#define MM11(av, bv) { __builtin_amdgcn_s_setprio(1);                               \
        _Pragma("unroll") for (int i = 0; i < 8; i++)                               \
            _Pragma("unroll") for (int j = 0; j < 3; j++)                           \
                acc[i][j] = __builtin_amdgcn_mfma_f32_16x16x32_bf16(                \
                    av[i], bv[j], acc[i][j], 0, 0, 0);                              \
        __builtin_amdgcn_s_setprio(0); }

    // prologue: stage tile 0 fully; leave A-kh1(0) in flight
    SA11(0, 0, 0);
    SB11(0, 0);
    SA11(0, 1, 0);
    WAIT_VM(2);
    __builtin_amdgcn_s_barrier();

    f32x4 acc[8][3] = {};
    for (int kt = 0; kt < NT; ++kt) {
        const int cur = kt & 1, nxt = cur ^ 1;
        const bool pf = (kt + 1 < NT);
        bf16x8 av[8], bv[3];
        // ph0: kh0
        RA11(av, cur, 0);
        RB11(bv, cur, 0);
        if (pf) SA11(nxt, 0, kt + 1);
        PHASE_HEAD();
        MM11(av, bv);
        if (pf) WAIT_VM(2); else WAIT_VM(0);   // force A-kh1(kt); gate BEFORE barrier
        __builtin_amdgcn_s_barrier();
        // ph1: kh1
        RA11(av, cur, 1);
        RB11(bv, cur, 1);
        if (pf) { SB11(nxt, kt + 1); SA11(nxt, 1, kt + 1); }
        PHASE_HEAD();
        MM11(av, bv);
        if (pf) {
            WAIT_VM(2);                        // force A-kh0(kt+1)+B(kt+1); kh1 in flight
            __builtin_amdgcn_s_barrier();
        }
    }

    if (cBf16) {
        unsigned short* C = (unsigned short*)Cout;
        #pragma unroll
        for (int i = 0; i < 8; i++)
            #pragma unroll
            for (int j = 0; j < 3; j++)
                #pragma unroll
                for (int r = 0; r < 4; r++) {
                    int row = row0 + wr * 128 + i * 16 + kq * 4 + r;
                    int col = col0 + wc * 48 + j * 16 + r16;
                    C[(size_t)row * N + col] = f2bf(acc[i][j][r]);
                }
    } else {
        float* C = (float*)Cout;
        #pragma unroll
        for (int i = 0; i < 8; i++)
            #pragma unroll
            for (int j = 0; j < 3; j++)
                #pragma unroll
                for (int r = 0; r < 4; r++) {
                    int row = row0 + wr * 128 + i * 16 + kq * 4 + r;
                    int col = col0 + wc * 48 + j * 16 + r16;
                    C[(size_t)row * N + col] = acc[i][j][r];
                }
    }
#undef SA11
#undef SB11
#undef RA11
#undef RB11
#undef MM11
}

// ---------------- O-proj GEMM: BM=256, BN=128, BK=64, 3-buf (r14 ledger) + PHASE_HEAD --
__global__ __launch_bounds__(512, 2) void gemm8n(
    const unsigned short* __restrict__ A, const unsigned short* __restrict__ Bt,
    float* __restrict__ C, int N, int lda, int Keff, int nbx) {
    __shared__ __align__(16) unsigned short Abuf[3][256 * 64];  // 96 KB
    __shared__ __align__(16) unsigned short Bbuf[3][128 * 64];  // 48 KB

    const int inner = blockIdx.x;
    const int cbx = nbx >> 3;
    const int xcd = inner & 7, kk = inner >> 3;
    const int bx = xcd * cbx + (kk % cbx);
    const int by = kk / cbx;
    const int row0 = by * 256, col0 = bx * 128;

    const int t = threadIdx.x, lane = t & 63, w = t >> 6;
    const int wr = w >> 1, wc = w & 1;          // 4M x 2N wave grid
    const int r16 = lane & 15, kq = lane >> 4;

    const int srow = t >> 3;                    // 0..63
    const int scsw = (t & 7) ^ (srow & 7);
    const unsigned short* aStage = A  + (size_t)(row0 + srow) * lda + scsw * 8;
    const unsigned short* bStage = Bt + (size_t)(col0 + srow) * lda + scsw * 8;
    const size_t rstep = 64 * (size_t)lda;

    const int NT = Keff / 64;

#define NSTG_H0(bufi, kt) {                                                     \
        gload16(aStage + (size_t)(kt) * 64,             &Abuf[bufi][0 * 4096 + w * 512]); \
        gload16(aStage + (size_t)(kt) * 64 + rstep,     &Abuf[bufi][1 * 4096 + w * 512]); \
        gload16(bStage + (size_t)(kt) * 64,             &Bbuf[bufi][0 * 4096 + w * 512]); }
#define NSTG_H1(bufi, kt) {                                                     \
        gload16(aStage + (size_t)(kt) * 64 + 2 * rstep, &Abuf[bufi][2 * 4096 + w * 512]); \
        gload16(aStage + (size_t)(kt) * 64 + 3 * rstep, &Abuf[bufi][3 * 4096 + w * 512]); \
        gload16(bStage + (size_t)(kt) * 64 + rstep,     &Bbuf[bufi][1 * 4096 + w * 512]); }

#define NLDA(dst, bufi, kh) { _Pragma("unroll") for (int i = 0; i < 4; i++) {   \
        int ar = wr * 64 + i * 16 + r16;                                        \
        dst[i] = *(const bf16x8*)&Abuf[bufi][ar * 64 + (((kh) * 4 + kq) ^ (ar & 7)) * 8]; } }
#define NLDB(dst, bufi, kh) { _Pragma("unroll") for (int j = 0; j < 4; j++) {   \
        int br = wc * 64 + j * 16 + r16;                                        \
        dst[j] = *(const bf16x8*)&Bbuf[bufi][br * 64 + (((kh) * 4 + kq) ^ (br & 7)) * 8]; } }

#define MMN(av, bv) {                                                           \
        __builtin_amdgcn_s_setprio(1);                                          \
        _Pragma("unroll") for (int i = 0; i < 4; i++)                           \
            _Pragma("unroll") for (int j = 0; j < 4; j++)                       \
                acc[i][j] = __builtin_amdgcn_mfma_f32_16x16x32_bf16(            \
                    av[i], bv[j], acc[i][j], 0, 0, 0);                          \
        __builtin_amdgcn_s_setprio(0); }

    NSTG_H0(0, 0); NSTG_H1(0, 0);
    NSTG_H0(1, 1); NSTG_H1(1, 1);
    WAIT_VM(6);
    __builtin_amdgcn_s_barrier();

    f32x4 acc[4][4] = {};
    for (int kt = 0; kt < NT; ++kt) {
        const int cur = kt % 3, nx2 = (kt + 2) % 3;
        const bool pf = (kt + 2) < NT;
        bf16x8 av[4], bv[4];
        // ph0
        NLDA(av, cur, 0);
        NLDB(bv, cur, 0);
        if (pf) NSTG_H0(nx2, kt + 2);
        PHASE_HEAD();
        MMN(av, bv);
        __builtin_amdgcn_s_barrier();
        // ph1
        NLDA(av, cur, 1);
        NLDB(bv, cur, 1);
        if (pf) NSTG_H1(nx2, kt + 2);
        PHASE_HEAD();
        MMN(av, bv);
        if (kt + 1 < NT) {
            if (pf) WAIT_VM(6); else WAIT_VM(0);   // gate BEFORE barrier (r17 lesson)
            __builtin_amdgcn_s_barrier();
        }
    }

    #pragma unroll
    for (int i = 0; i < 4; i++)
        #pragma unroll
        for (int j = 0; j < 4; j++)
            #pragma unroll
            for (int r = 0; r < 4; r++) {
                int row = row0 + wr * 64 + i * 16 + kq * 4 + r;
                int col = col0 + wc * 64 + j * 16 + r16;
                C[(size_t)row * N + col] = acc[i][j][r];
            }
#undef NSTG_H0
#undef NSTG_H1
#undef NLDA
#undef NLDB
#undef MMN
}

// ---------------- RoPE + convert to head-major bf16 (reads fused qkv bf16) -------------
__global__ void rope_convert(const unsigned short* __restrict__ qkvb,
                             unsigned short* __restrict__ qb, unsigned short* __restrict__ kb) {
    const int s = blockIdx.x;
    const int head = blockIdx.y;
    const int d = threadIdx.x;  // 0..63
    const float SCALE = 0.08838834764831845f;  // 1/sqrt(128)
    const float NLOG = -0.14391156831212787f;  // -ln(10000)/64
    float f = (float)s * __expf((float)d * NLOG);
    float sn, c;
    __sincosf(f, &sn, &c);
    if (head < NQH) {
        const unsigned short* src = qkvb + (size_t)s * QKVN + head * DHEAD;
        float x1 = bf2f(src[d]), x2 = bf2f(src[d + 64]);
        unsigned short* dst = qb + ((size_t)head * SEQ + s) * DHEAD;
        dst[d]      = f2bf((x1 * c - x2 * sn) * SCALE);
        dst[d + 64] = f2bf((x2 * c + x1 * sn) * SCALE);
    } else {
        const int hk = head - NQH;
        const unsigned short* src = qkvb + (size_t)s * QKVN + 4096 + hk * DHEAD;
        float x1 = bf2f(src[d]), x2 = bf2f(src[d + 64]);
        unsigned short* dst = kb + ((size_t)hk * SEQ + s) * DHEAD;
        dst[d]      = f2bf(x1 * c - x2 * sn);
        dst[d + 64] = f2bf(x2 * c + x1 * sn);
    }
}

// ---------------- Flash attention: swapped QK^T + in-register softmax (32x32 MFMA) -----
__global__ __launch_bounds__(256, 2) void attention_kernel(
    const unsigned short* __restrict__ Q, const unsigned short* __restrict__ K,
    const unsigned short* __restrict__ Vt, unsigned short* __restrict__ O) {
    __shared__ __align__(16) unsigned short Ks[64 * 128];  // [kcol][d], swizzled
    __shared__ __align__(16) unsigned short Vs[128 * 64];  // [d][k],   swizzled
    const int h = blockIdx.x & 31;
    const int p = 15 - (blockIdx.x >> 5);   // LPT: largest slabs first
    const int t = threadIdx.x, lane = t & 63, w = t >> 6;
    const int q31 = lane & 31, h2 = lane >> 5;
    const int q0w = p * 128 + w * 32;
    const int kbw = 2 * p + (w >> 1);       // this warp's diagonal kb
    const int kbmax = 2 * p + 1;            // block's last kb
    const int hkv = h >> 2;

    bf16x8 qf[8];
    {
        const unsigned short* qrow = Q + ((size_t)h * SEQ + q0w + q31) * DHEAD + h2 * 8;
        #pragma unroll
        for (int ds = 0; ds < 8; ds++) qf[ds] = *(const bf16x8*)&qrow[ds * 16];
    }

    f32x16 oacc[4] = {};
    float m_r = -1e30f, l_r = 0.f;

    const unsigned short* Kg = K + (size_t)hkv * SEQ * DHEAD;
    const unsigned short* Vg = Vt + (size_t)hkv * DHEAD * SEQ;

    const int krow = t >> 4, kch = t & 15;
    const int vrow = t >> 3, vch = t & 7;
    ushort8 kreg[4], vreg[4];
    #pragma unroll
    for (int pp = 0; pp < 4; pp++) {
        kreg[pp] = *(const ushort8*)&Kg[(size_t)(pp * 16 + krow) * DHEAD + kch * 8];
        vreg[pp] = *(const ushort8*)&Vg[(size_t)(pp * 32 + vrow) * SEQ + vch * 8];
    }

    for (int kb = 0; kb <= kbmax; ++kb) {
        __syncthreads();
        #pragma unroll
        for (int pp = 0; pp < 4; pp++) {
            int row = pp * 16 + krow;
            *(ushort8*)&Ks[row * 128 + ((kch ^ (row & 7)) * 8)] = kreg[pp];
            int vr = pp * 32 + vrow;
            *(ushort8*)&Vs[vr * 64 + ((vch ^ (vr & 7)) * 8)] = vreg[pp];
        }
        if (kb < kbmax) {
            #pragma unroll
            for (int pp = 0; pp < 4; pp++) {
                kreg[pp] = *(const ushort8*)&Kg[(size_t)((kb + 1) * 64 + pp * 16 + krow) * DHEAD + kch * 8];
                vreg[pp] = *(const ushort8*)&Vg[(size_t)(pp * 32 + vrow) * SEQ + (kb + 1) * 64 + vch * 8];
            }
        }
        __syncthreads();
        if (kb > kbw) continue;

        f32x16 s0 = {}, s1 = {};
        #pragma unroll
        for (int ds = 0; ds < 8; ds++) {
            int r0 = q31;
            int c0 = (ds * 2 + h2) ^ (r0 & 7);
            bf16x8 kf0 = *(const bf16x8*)&Ks[r0 * 128 + c0 * 8];
            s0 = __builtin_amdgcn_mfma_f32_32x32x16_bf16(kf0, qf[ds], s0, 0, 0, 0);
            int r1 = 32 + q31;
            int c1 = (ds * 2 + h2) ^ (r1 & 7);
            bf16x8 kf1 = *(const bf16x8*)&Ks[r1 * 128 + c1 * 8];
            s1 = __builtin_amdgcn_mfma_f32_32x32x16_bf16(kf1, qf[ds], s1, 0, 0, 0);
        }
        if (kb == kbw) {
            const int qg = q0w + q31;
            #pragma unroll
            for (int r = 0; r < 16; r++) {
                int kpos = (r & 3) + 8 * (r >> 2) + 4 * h2;
                s0[r] = (kb * 64 + kpos > qg) ? -1e30f : s0[r];
                s1[r] = (kb * 64 + 32 + kpos > qg) ? -1e30f : s1[r];
            }
        }
        float pm = -1e30f;
        #pragma unroll
        for (int r = 0; r < 16; r++) pm = fmaxf(pm, fmaxf(s0[r], s1[r]));
        pm = fmaxf(pm, __shfl_xor(pm, 32));
        bool grow = pm > m_r + 8.f;
        if (__any(grow)) {
            float mn = fmaxf(m_r, pm);
            float sc = __expf(m_r - mn);
            l_r *= sc;
            float scr[16];
            #pragma unroll
            for (int r = 0; r < 16; r++) scr[r] = __shfl(sc, (r & 3) + 8 * (r >> 2) + 4 * h2);
            #pragma unroll
            for (int nt = 0; nt < 4; nt++)
                #pragma unroll
                for (int r = 0; r < 16; r++) oacc[nt][r] *= scr[r];
            m_r = mn;
        }
        float sum = 0.f;
        #pragma unroll
        for (int r = 0; r < 16; r++) {
            s0[r] = __expf(s0[r] - m_r); sum += s0[r];
            s1[r] = __expf(s1[r] - m_r); sum += s1[r];
        }
        sum += __shfl_xor(sum, 32);
        l_r += sum;
        unsigned ow0[8], ow1[8];
        #pragma unroll
        for (int a = 0; a < 4; a++) {
            ow0[a * 2 + 0] = cvtpk(s0[4 * a + 0], s0[4 * a + 1]);
            ow0[a * 2 + 1] = cvtpk(s0[4 * a + 2], s0[4 * a + 3]);
            ow1[a * 2 + 0] = cvtpk(s1[4 * a + 0], s1[4 * a + 1]);
            ow1[a * 2 + 1] = cvtpk(s1[4 * a + 2], s1[4 * a + 3]);
        }
        unsigned pw0[8], pw1[8];
        #pragma unroll
        for (int i = 0; i < 8; i++) {
            pw0[i] = __shfl_xor((int)ow0[i], 32);
            pw1[i] = __shfl_xor((int)ow1[i], 32);
        }
        bf16x8 pf[4];
        const bool lo = (h2 == 0);
        #pragma unroll
        for (int sub = 0; sub < 2; sub++) {
            int b0 = 2 * sub, b1 = 2 * sub + 1;
            u32x4 t0, t1;
            t0.x = lo ? ow0[b0 * 2 + 0] : pw0[b1 * 2 + 0];
            t0.y = lo ? ow0[b0 * 2 + 1] : pw0[b1 * 2 + 1];
            t0.z = lo ? pw0[b0 * 2 + 0] : ow0[b1 * 2 + 0];
            t0.w = lo ? pw0[b0 * 2 + 1] : ow0[b1 * 2 + 1];
            pf[sub] = __builtin_bit_cast(bf16x8, t0);
            t1.x = lo ? ow1[b0 * 2 + 0] : pw1[b1 * 2 + 0];
            t1.y = lo ? ow1[b0 * 2 + 1] : pw1[b1 * 2 + 1];
            t1.z = lo ? pw1[b0 * 2 + 0] : ow1[b1 * 2 + 0];
            t1.w = lo ? pw1[b0 * 2 + 1] : ow1[b1 * 2 + 1];
            pf[2 + sub] = __builtin_bit_cast(bf16x8, t1);
        }
        #pragma unroll
        for (int nt = 0; nt < 4; nt++) {
            int vr2 = nt * 32 + q31;
            #pragma unroll
            for (int kt16 = 0; kt16 < 4; kt16++) {
                int vc2 = (kt16 * 2 + h2) ^ (vr2 & 7);
                bf16x8 vf = *(const bf16x8*)&Vs[vr2 * 64 + vc2 * 8];
                oacc[nt] = __builtin_amdgcn_mfma_f32_32x32x16_bf16(pf[kt16], vf, oacc[nt], 0, 0, 0);
            }
        }
    }
    float inv = 1.0f / l_r;
    float invr[16];
    #pragma unroll
    for (int r = 0; r < 16; r++) invr[r] = __shfl(inv, (r & 3) + 8 * (r >> 2) + 4 * h2);
    #pragma unroll
    for (int nt = 0; nt < 4; nt++)
        #pragma unroll
        for (int r = 0; r < 16; r++) {
            int qg = q0w + (r & 3) + 8 * (r >> 2) + 4 * h2;
            O[(size_t)qg * HDIM + h * DHEAD + nt * 32 + q31] = f2bf(oacc[nt][r] * invr[r]);
        }
}

extern "C" void kernel_launch(void* const* d_in, const int* in_sizes, int n_in,
                              void* d_out, int out_size, void* d_ws, size_t ws_size,
                              hipStream_t stream) {
    const float* hs  = (const float*)d_in[0];
    const float* lnw = (const float*)d_in[1];
    const float* lnb = (const float*)d_in[2];
    const float* wq  = (const float*)d_in[3];
    const float* wk  = (const float*)d_in[4];
    const float* wv  = (const float*)d_in[5];
    const float* wo  = (const float*)d_in[6];
    float* out = (float*)d_out;

    char* ws = (char*)d_ws;
    size_t off = 0;
    auto alloc = [&](size_t bytes) {
        void* p = ws + off;
        off += (bytes + 255) & ~(size_t)255;
        return p;
    };
    unsigned short* xb   = (unsigned short*)alloc((size_t)SEQ * HDIM * 2);
    // wqT/wkT/wvT contiguous -> fused [6144][4096] B matrix
    unsigned short* wqT  = (unsigned short*)alloc((size_t)HDIM * (NQH * DHEAD) * 2);
    unsigned short* wkT  = (unsigned short*)alloc((size_t)HDIM * (NKVH * DHEAD) * 2);
    unsigned short* wvT  = (unsigned short*)alloc((size_t)HDIM * (NKVH * DHEAD) * 2);
    unsigned short* woT  = (unsigned short*)alloc((size_t)(NQH * DHEAD) * HDIM * 2);
    unsigned short* qkvb = (unsigned short*)alloc((size_t)SEQ * QKVN * 2);
    unsigned short* qbuf = (unsigned short*)alloc((size_t)NQH * SEQ * DHEAD * 2);
    unsigned short* kbuf = (unsigned short*)alloc((size_t)NKVH * SEQ * DHEAD * 2);
    unsigned short* vbt  = (unsigned short*)alloc((size_t)NKVH * DHEAD * SEQ * 2);
    unsigned short* attnb = qkvb;  // overlay: qkv consumed by rope/transpose_v before attention

    dim3 tb(32, 8);
    transpose_convert<<<dim3(4096 / 32, 4096 / 64), tb, 0, stream>>>(wq, wqT, 4096, 4096);
    transpose_convert<<<dim3(1024 / 32, 4096 / 64), tb, 0, stream>>>(wk, wkT, 4096, 1024);
    transpose_convert<<<dim3(1024 / 32, 4096 / 64), tb, 0, stream>>>(wv, wvT, 4096, 1024);
    transpose_convert<<<dim3(4096 / 32, 4096 / 64), tb, 0, stream>>>(wo, woT, 4096, 4096);

    layernorm_kernel<<<SEQ, 256, 0, stream>>>(hs, lnw, lnb, xb);

    // fused QKV projection (bf16 out): BM=256 x BN=192 -> grid 8 x 32 = 256 (full chip)
    gemm11<<<(2048 / 256) * (QKVN / 192), 512, 0, stream>>>(
        xb, wqT, qkvb, QKVN, 4096, 4096, QKVN / 192, 1);

    rope_convert<<<dim3(SEQ, NQH + NKVH), 64, 0, stream>>>(qkvb, qbuf, kbuf);
    transpose_v<<<dim3(SEQ / 32, DHEAD / 32, NKVH), tb, 0, stream>>>(qkvb, vbt);

    // swapped-QK attention: grid = 32 heads x 16 q-slabs (128 rows each), 4 warps/block
    attention_kernel<<<NQH * 16, 256, 0, stream>>>(qbuf, kbuf, vbt, attnb);

    // O-proj: full K=4096, grid 8 x 32 = 256 blocks exactly
    gemm8n<<<(2048 / 256) * (4096 / 128), 512, 0, stream>>>(
        attnb, woT, out, 4096, 4096, 4096, 4096 / 128);
}

// Round 19
// 306.326 us; speedup vs baseline: 1.0564x; 1.0564x over previous
//
#include <hip/hip_runtime.h>
#include <hip/hip_bf16.h>

#define HDIM 4096
#define DHEAD 128
#define NQH 32
#define NKVH 8
#define SEQ 2048
#define QKVN 6144  // fused N = 4096 + 1024 + 1024

typedef __bf16 bf16x8 __attribute__((ext_vector_type(8)));
typedef unsigned short ushort8 __attribute__((ext_vector_type(8)));
typedef float f32x4 __attribute__((ext_vector_type(4)));
typedef float f32x16 __attribute__((ext_vector_type(16)));
typedef unsigned int u32x4 __attribute__((ext_vector_type(4)));

// wait until <= N vector-memory ops outstanding (lgkm/exp not waited)
#define WAIT_VM(N) __builtin_amdgcn_s_waitcnt(0xF70 | (N))

__device__ inline unsigned short f2bf(float f) {
    unsigned u = __float_as_uint(f);
    u += 0x7fffu + ((u >> 16) & 1u);
    return (unsigned short)(u >> 16);
}

__device__ inline float bf2f(unsigned short u) {
    return __uint_as_float(((unsigned)u) << 16);
}

// pack two f32 -> {lo:bf16, hi:bf16} in one u32 (low word = first arg)
__device__ inline unsigned cvtpk(float lo, float hi) {
    unsigned r;
    asm("v_cvt_pk_bf16_f32 %0, %1, %2" : "=v"(r) : "v"(lo), "v"(hi));
    return r;
}

__device__ inline void gload16(const void* g, void* l) {
    __builtin_amdgcn_global_load_lds(
        (const __attribute__((address_space(1))) unsigned int*)g,
        (__attribute__((address_space(3))) unsigned int*)l, 16, 0, 0);
}

// ------- merged weight transpose + fp32->bf16: 4 weights in one launch (z-indexed) -----
// in[K=4096][N] -> out[N][K]; 64k x 32n tiles; uint writes (2 bf16) -> 128B segments.
// z: 0=wq(N=4096) 1=wk(1024) 2=wv(1024) 3=wo(4096); off-range blocks exit pre-barrier.
__global__ void transpose_convert_all(
    const float* __restrict__ wq, const float* __restrict__ wk,
    const float* __restrict__ wv, const float* __restrict__ wo,
    unsigned short* __restrict__ wqT, unsigned short* __restrict__ wkT,
    unsigned short* __restrict__ wvT, unsigned short* __restrict__ woT) {
    const int z = blockIdx.z;
    const float* in;
    unsigned short* out;
    int N;
    if (z == 0)      { in = wq; out = wqT; N = 4096; }
    else if (z == 1) { in = wk; out = wkT; N = 1024; }
    else if (z == 2) { in = wv; out = wvT; N = 1024; }
    else             { in = wo; out = woT; N = 4096; }
    const int n0 = blockIdx.x * 32, k0 = blockIdx.y * 64;
    if (n0 >= N) return;  // block-uniform exit (before any barrier)
    __shared__ float tile[64][33];
    const int tx = threadIdx.x, ty = threadIdx.y;  // 32 x 8
    #pragma unroll
    for (int r = 0; r < 8; r++)
        tile[ty + r * 8][tx] = in[(size_t)(k0 + ty + r * 8) * N + n0 + tx];
    __syncthreads();
    #pragma unroll
    for (int r = 0; r < 4; r++) {
        int n = ty + r * 8;
        unsigned v = (unsigned)f2bf(tile[tx * 2][n]) |
                     ((unsigned)f2bf(tile[tx * 2 + 1][n]) << 16);
        *(unsigned*)&out[(size_t)(n0 + n) * 4096 + k0 + tx * 2] = v;
    }
}

// ---------------- V transpose: bf16 qkv-fused row -> bf16 (NKVH, D, S) ----------------
__global__ void transpose_v(const unsigned short* __restrict__ qkvb,
                            unsigned short* __restrict__ vbt) {
    __shared__ unsigned short tile[32][34];
    const int s0 = blockIdx.x * 32, d0 = blockIdx.y * 32, hv = blockIdx.z;
    const int tx = threadIdx.x, ty = threadIdx.y;  // 32 x 8
    for (int r = 0; r < 32; r += 8)
        tile[ty + r][tx] = qkvb[(size_t)(s0 + ty + r) * QKVN + 5120 + hv * DHEAD + d0 + tx];
    __syncthreads();
    for (int r = 0; r < 32; r += 8)
        vbt[((size_t)hv * DHEAD + d0 + ty + r) * SEQ + s0 + tx] = tile[tx][ty + r];
}

// ---------------- LayerNorm: fp32 (S,H) -> bf16 (S,H) ----------------
__global__ __launch_bounds__(256) void layernorm_kernel(
    const float* __restrict__ hs, const float* __restrict__ w, const float* __restrict__ b,
    unsigned short* __restrict__ xb) {
    const int s = blockIdx.x;
    const float* row = hs + (size_t)s * HDIM;
    const int t = threadIdx.x;
    float vals[16];
    float sum = 0.f, sq = 0.f;
    for (int j = 0; j < 16; j++) {
        float v = row[j * 256 + t];
        vals[j] = v; sum += v; sq += v * v;
    }
    for (int off = 1; off < 64; off <<= 1) {
        sum += __shfl_xor(sum, off);
        sq  += __shfl_xor(sq, off);
    }
    __shared__ float ps[4], pq[4];
    if ((t & 63) == 0) { ps[t >> 6] = sum; pq[t >> 6] = sq; }
    __syncthreads();
    sum = ps[0] + ps[1] + ps[2] + ps[3];
    sq  = pq[0] + pq[1] + pq[2] + pq[3];
    const float mu = sum * (1.0f / HDIM);
    const float var = sq * (1.0f / HDIM) - mu * mu;
    const float rs = rsqrtf(var + 1e-5f);
    for (int j = 0; j < 16; j++) {
        int i = j * 256 + t;
        xb[(size_t)s * HDIM + i] = f2bf((vals[j] - mu) * rs * w[i] + b[i]);
    }
}

// ------- gemm11 (QKV): BM=256, BN=192, BK=64 -> grid 8 x 32 = 256 blocks (full chip) ---
// r16 best config: counted-vmcnt single-gate schedule (NO barrier-pair phase heads —
// r7/r13/r18 all show those regress here). Ledger:
//   ph0 gate WAIT_VM(2)->barrier forces A-kh1(kt); ph1 gate WAIT_VM(2)->barrier forces
//   A-kh0+B of kt+1; A-kh1(kt+1) stays in flight.
__global__ __launch_bounds__(512, 1) void gemm11(
    const unsigned short* __restrict__ A, const unsigned short* __restrict__ Bt,
    void* __restrict__ Cout, int N, int lda, int Keff, int nbx, int cBf16) {
    __shared__ __align__(16) unsigned short Abuf[2 * 2 * 256 * 32];  // 64 KB
    __shared__ __align__(16) unsigned short Bbuf[2 * 192 * 64];      // 48 KB

    const int inner = blockIdx.x;
    const int cbx = nbx >> 3;
    const int xcd = inner & 7, k = inner >> 3;
    const int bx = xcd * cbx + (k % cbx);
    const int by = k / cbx;
    const int row0 = by * 256, col0 = bx * 192;

    const int t = threadIdx.x, lane = t & 63, w = t >> 6;
    const int wr = w >> 2, wc = w & 3;          // 2M x 4N wave grid
    const int r16 = lane & 15, kq = lane >> 4;

    const int srowA = t >> 2;
    const int scswA = (t & 3) ^ ((srowA >> 1) & 3);
    const unsigned short* aS = A + (size_t)(row0 + srowA) * lda + scswA * 8;
    const int srowB = t >> 3;
    const int scswB = (t & 7) ^ (srowB & 7);
    const unsigned short* bS = Bt + (size_t)(col0 + srowB) * lda + scswB * 8;
    const size_t a128 = 128 * (size_t)lda;
    const size_t b64 = 64 * (size_t)lda;
    const int wdst = w * 512;

    const int NT = Keff / 64;

#define SA11(bufi, kh, kt) {                                                        \
        const unsigned short* _g = aS + (size_t)(kt) * 64 + (kh) * 32;              \
        gload16(_g,        &Abuf[(bufi) * 16384 + (kh) * 8192 + wdst]);             \
        gload16(_g + a128, &Abuf[(bufi) * 16384 + (kh) * 8192 + 4096 + wdst]); }
#define SB11(bufi, kt) {                                                            \
        const unsigned short* _g = bS + (size_t)(kt) * 64;                          \
        gload16(_g,            &Bbuf[(bufi) * 12288 + wdst]);                       \
        gload16(_g + b64,      &Bbuf[(bufi) * 12288 + 4096 + wdst]);                \
        gload16(_g + 2 * b64,  &Bbuf[(bufi) * 12288 + 8192 + wdst]); }
#define RA11(dst, bufi, kh) { _Pragma("unroll") for (int i = 0; i < 8; i++) {       \
        int ar = wr * 128 + i * 16 + r16;                                           \
        dst[i] = *(const bf16x8*)&Abuf[(bufi) * 16384 + (kh) * 8192 + ar * 32 +     \
                 (kq ^ ((ar >> 1) & 3)) * 8]; } }
#define RB11(dst, bufi, kh) { _Pragma("unroll") for (int j = 0; j < 3; j++) {       \
        int br = wc * 48 + j * 16 + r16;                                            \
        dst[j] = *(const bf16x8*)&Bbuf[(bufi) * 12288 + br * 64 +                   \
                 ((((kh) * 4) + kq) ^ (br & 7)) * 8]; } }
#define MM11(av, bv) { __builtin_amdgcn_s_setprio(1);                               \
        _Pragma("unroll") for (int i = 0; i < 8; i++)                               \
            _Pragma("unroll") for (int j = 0; j < 3; j++)                           \
                acc[i][j] = __builtin_amdgcn_mfma_f32_16x16x32_bf16(                \
                    av[i], bv[j], acc[i][j], 0, 0, 0);                              \
        __builtin_amdgcn_s_setprio(0); }

    // prologue: stage tile 0 fully; leave A-kh1(0) in flight
    SA11(0, 0, 0);
    SB11(0, 0);
    SA11(0, 1, 0);
    WAIT_VM(2);
    __builtin_amdgcn_s_barrier();

    f32x4 acc[8][3] = {};
    for (int kt = 0; kt < NT; ++kt) {
        const int cur = kt & 1, nxt = cur ^ 1;
        const bool pf = (kt + 1 < NT);
        bf16x8 av[8], bv[3];
        // ph0: kh0
        RA11(av, cur, 0);
        RB11(bv, cur, 0);
        if (pf) SA11(nxt, 0, kt + 1);
        MM11(av, bv);
        if (pf) WAIT_VM(2); else WAIT_VM(0);   // force A-kh1(kt) landed
        __builtin_amdgcn_s_barrier();
        // ph1: kh1
        RA11(av, cur, 1);
        RB11(bv, cur, 1);
        if (pf) { SB11(nxt, kt + 1); SA11(nxt, 1, kt + 1); }
        MM11(av, bv);
        if (pf) {
            WAIT_VM(2);                        // force A-kh0(kt+1)+B(kt+1); kh1 in flight
            __builtin_amdgcn_s_barrier();
        }
    }

    if (cBf16) {
        unsigned short* C = (unsigned short*)Cout;
        #pragma unroll
        for (int i = 0; i < 8; i++)
            #pragma unroll
            for (int j = 0; j < 3; j++)
                #pragma unroll
                for (int r = 0; r < 4; r++) {
                    int row = row0 + wr * 128 + i * 16 + kq * 4 + r;
                    int col = col0 + wc * 48 + j * 16 + r16;
                    C[(size_t)row * N + col] = f2bf(acc[i][j][r]);
                }
    } else {
        float* C = (float*)Cout;
        #pragma unroll
        for (int i = 0; i < 8; i++)
            #pragma unroll
            for (int j = 0; j < 3; j++)
                #pragma unroll
                for (int r = 0; r < 4; r++) {
                    int row = row0 + wr * 128 + i * 16 + kq * 4 + r;
                    int col = col0 + wc * 48 + j * 16 + r16;
                    C[(size_t)row * N + col] = acc[i][j][r];
                }
    }
#undef SA11
#undef SB11
#undef RA11
#undef RB11
#undef MM11
}

// ---------------- O-proj GEMM: BM=256, BN=128, BK=64, 3-buf counted vmcnt (r12/r14) ----
__global__ __launch_bounds__(512, 2) void gemm8n(
    const unsigned short* __restrict__ A, const unsigned short* __restrict__ Bt,
    float* __restrict__ C, int N, int lda, int Keff, int nbx) {
    __shared__ __align__(16) unsigned short Abuf[3][256 * 64];  // 96 KB
    __shared__ __align__(16) unsigned short Bbuf[3][128 * 64];  // 48 KB

    const int inner = blockIdx.x;
    const int cbx = nbx >> 3;
    const int xcd = inner & 7, kk = inner >> 3;
    const int bx = xcd * cbx + (kk % cbx);
    const int by = kk / cbx;
    const int row0 = by * 256, col0 = bx * 128;

    const int t = threadIdx.x, lane = t & 63, w = t >> 6;
    const int wr = w >> 1, wc = w & 1;          // 4M x 2N wave grid
    const int r16 = lane & 15, kq = lane >> 4;

    const int srow = t >> 3;                    // 0..63
    const int scsw = (t & 7) ^ (srow & 7);
    const unsigned short* aStage = A  + (size_t)(row0 + srow) * lda + scsw * 8;
    const unsigned short* bStage = Bt + (size_t)(col0 + srow) * lda + scsw * 8;
    const size_t rstep = 64 * (size_t)lda;

    const int NT = Keff / 64;

#define NSTG_H0(bufi, kt) {                                                     \
        gload16(aStage + (size_t)(kt) * 64,             &Abuf[bufi][0 * 4096 + w * 512]); \
        gload16(aStage + (size_t)(kt) * 64 + rstep,     &Abuf[bufi][1 * 4096 + w * 512]); \
        gload16(bStage + (size_t)(kt) * 64,             &Bbuf[bufi][0 * 4096 + w * 512]); }
#define NSTG_H1(bufi, kt) {                                                     \
        gload16(aStage + (size_t)(kt) * 64 + 2 * rstep, &Abuf[bufi][2 * 4096 + w * 512]); \
        gload16(aStage + (size_t)(kt) * 64 + 3 * rstep, &Abuf[bufi][3 * 4096 + w * 512]); \
        gload16(bStage + (size_t)(kt) * 64 + rstep,     &Bbuf[bufi][1 * 4096 + w * 512]); }

#define NLDA(dst, bufi, kh) { _Pragma("unroll") for (int i = 0; i < 4; i++) {   \
        int ar = wr * 64 + i * 16 + r16;                                        \
        dst[i] = *(const bf16x8*)&Abuf[bufi][ar * 64 + (((kh) * 4 + kq) ^ (ar & 7)) * 8]; } }
#define NLDB(dst, bufi, kh) { _Pragma("unroll") for (int j = 0; j < 4; j++) {   \
        int br = wc * 64 + j * 16 + r16;                                        \
        dst[j] = *(const bf16x8*)&Bbuf[bufi][br * 64 + (((kh) * 4 + kq) ^ (br & 7)) * 8]; } }

#define MMN(av, bv) {                                                           \
        __builtin_amdgcn_s_setprio(1);                                          \
        _Pragma("unroll") for (int i = 0; i < 4; i++)                           \
            _Pragma("unroll") for (int j = 0; j < 4; j++)                       \
                acc[i][j] = __builtin_amdgcn_mfma_f32_16x16x32_bf16(            \
                    av[i], bv[j], acc[i][j], 0, 0, 0);                          \
        __builtin_amdgcn_s_setprio(0); }

    NSTG_H0(0, 0); NSTG_H1(0, 0);
    NSTG_H0(1, 1); NSTG_H1(1, 1);
    WAIT_VM(6);
    __builtin_amdgcn_s_barrier();

    f32x4 acc[4][4] = {};
    for (int kt = 0; kt < NT; ++kt) {
        const int cur = kt % 3, nx2 = (kt + 2) % 3;
        const bool pf = (kt + 2) < NT;
        bf16x8 av[4], bv[4];
        NLDA(av, cur, 0);
        NLDB(bv, cur, 0);
        if (pf) NSTG_H0(nx2, kt + 2);
        MMN(av, bv);
        NLDA(av, cur, 1);
        NLDB(bv, cur, 1);
        if (pf) NSTG_H1(nx2, kt + 2);
        MMN(av, bv);
        if (kt + 1 < NT) {
            if (pf) WAIT_VM(6); else WAIT_VM(0);
            __builtin_amdgcn_s_barrier();
        }
    }

    #pragma unroll
    for (int i = 0; i < 4; i++)
        #pragma unroll
        for (int j = 0; j < 4; j++)
            #pragma unroll
            for (int r = 0; r < 4; r++) {
                int row = row0 + wr * 64 + i * 16 + kq * 4 + r;
                int col = col0 + wc * 64 + j * 16 + r16;
                C[(size_t)row * N + col] = acc[i][j][r];
            }
#undef NSTG_H0
#undef NSTG_H1
#undef NLDA
#undef NLDB
#undef MMN
}

// ---------------- RoPE + convert to head-major bf16 (reads fused qkv bf16) -------------
__global__ void rope_convert(const unsigned short* __restrict__ qkvb,
                             unsigned short* __restrict__ qb, unsigned short* __restrict__ kb) {
    const int s = blockIdx.x;
    const int head = blockIdx.y;
    const int d = threadIdx.x;  // 0..63
    const float SCALE = 0.08838834764831845f;  // 1/sqrt(128)
    const float NLOG = -0.14391156831212787f;  // -ln(10000)/64
    float f = (float)s * __expf((float)d * NLOG);
    float sn, c;
    __sincosf(f, &sn, &c);
    if (head < NQH) {
        const unsigned short* src = qkvb + (size_t)s * QKVN + head * DHEAD;
        float x1 = bf2f(src[d]), x2 = bf2f(src[d + 64]);
        unsigned short* dst = qb + ((size_t)head * SEQ + s) * DHEAD;
        dst[d]      = f2bf((x1 * c - x2 * sn) * SCALE);
        dst[d + 64] = f2bf((x2 * c + x1 * sn) * SCALE);
    } else {
        const int hk = head - NQH;
        const unsigned short* src = qkvb + (size_t)s * QKVN + 4096 + hk * DHEAD;
        float x1 = bf2f(src[d]), x2 = bf2f(src[d + 64]);
        unsigned short* dst = kb + ((size_t)hk * SEQ + s) * DHEAD;
        dst[d]      = f2bf(x1 * c - x2 * sn);
        dst[d + 64] = f2bf(x2 * c + x1 * sn);
    }
}

// ---------------- Flash attention: swapped QK^T + in-register softmax (32x32 MFMA) -----
__global__ __launch_bounds__(256, 2) void attention_kernel(
    const unsigned short* __restrict__ Q, const unsigned short* __restrict__ K,
    const unsigned short* __restrict__ Vt, unsigned short* __restrict__ O) {
    __shared__ __align__(16) unsigned short Ks[64 * 128];  // [kcol][d], swizzled
    __shared__ __align__(16) unsigned short Vs[128 * 64];  // [d][k],   swizzled
    const int h = blockIdx.x & 31;
    const int p = 15 - (blockIdx.x >> 5);   // LPT: largest slabs first
    const int t = threadIdx.x, lane = t & 63, w = t >> 6;
    const int q31 = lane & 31, h2 = lane >> 5;
    const int q0w = p * 128 + w * 32;
    const int kbw = 2 * p + (w >> 1);       // this warp's diagonal kb
    const int kbmax = 2 * p + 1;            // block's last kb
    const int hkv = h >> 2;

    bf16x8 qf[8];
    {
        const unsigned short* qrow = Q + ((size_t)h * SEQ + q0w + q31) * DHEAD + h2 * 8;
        #pragma unroll
        for (int ds = 0; ds < 8; ds++) qf[ds] = *(const bf16x8*)&qrow[ds * 16];
    }

    f32x16 oacc[4] = {};
    float m_r = -1e30f, l_r = 0.f;

    const unsigned short* Kg = K + (size_t)hkv * SEQ * DHEAD;
    const unsigned short* Vg = Vt + (size_t)hkv * DHEAD * SEQ;

    const int krow = t >> 4, kch = t & 15;
    const int vrow = t >> 3, vch = t & 7;
    ushort8 kreg[4], vreg[4];
    #pragma unroll
    for (int pp = 0; pp < 4; pp++) {
        kreg[pp] = *(const ushort8*)&Kg[(size_t)(pp * 16 + krow) * DHEAD + kch * 8];
        vreg[pp] = *(const ushort8*)&Vg[(size_t)(pp * 32 + vrow) * SEQ + vch * 8];
    }

    for (int kb = 0; kb <= kbmax; ++kb) {
        __syncthreads();
        #pragma unroll
        for (int pp = 0; pp < 4; pp++) {
            int row = pp * 16 + krow;
            *(ushort8*)&Ks[row * 128 + ((kch ^ (row & 7)) * 8)] = kreg[pp];
            int vr = pp * 32 + vrow;
            *(ushort8*)&Vs[vr * 64 + ((vch ^ (vr & 7)) * 8)] = vreg[pp];
        }
        if (kb < kbmax) {
            #pragma unroll
            for (int pp = 0; pp < 4; pp++) {
                kreg[pp] = *(const ushort8*)&Kg[(size_t)((kb + 1) * 64 + pp * 16 + krow) * DHEAD + kch * 8];
                vreg[pp] = *(const ushort8*)&Vg[(size_t)(pp * 32 + vrow) * SEQ + (kb + 1) * 64 + vch * 8];
            }
        }
        __syncthreads();
        if (kb > kbw) continue;

        f32x16 s0 = {}, s1 = {};
        #pragma unroll
        for (int ds = 0; ds < 8; ds++) {
            int r0 = q31;
            int c0 = (ds * 2 + h2) ^ (r0 & 7);
            bf16x8 kf0 = *(const bf16x8*)&Ks[r0 * 128 + c0 * 8];
            s0 = __builtin_amdgcn_mfma_f32_32x32x16_bf16(kf0, qf[ds], s0, 0, 0, 0);
            int r1 = 32 + q31;
            int c1 = (ds * 2 + h2) ^ (r1 & 7);
            bf16x8 kf1 = *(const bf16x8*)&Ks[r1 * 128 + c1 * 8];
            s1 = __builtin_amdgcn_mfma_f32_32x32x16_bf16(kf1, qf[ds], s1, 0, 0, 0);
        }
        if (kb == kbw) {
            const int qg = q0w + q31;
            #pragma unroll
            for (int r = 0; r < 16; r++) {
                int kpos = (r & 3) + 8 * (r >> 2) + 4 * h2;
                s0[r] = (kb * 64 + kpos > qg) ? -1e30f : s0[r];
                s1[r] = (kb * 64 + 32 + kpos > qg) ? -1e30f : s1[r];
            }
        }
        float pm = -1e30f;
        #pragma unroll
        for (int r = 0; r < 16; r++) pm = fmaxf(pm, fmaxf(s0[r], s1[r]));
        pm = fmaxf(pm, __shfl_xor(pm, 32));
        bool grow = pm > m_r + 8.f;
        if (__any(grow)) {
            float mn = fmaxf(m_r, pm);
            float sc = __expf(m_r - mn);
            l_r *= sc;
            float scr[16];
            #pragma unroll
            for (int r = 0; r < 16; r++) scr[r] = __shfl(sc, (r & 3) + 8 * (r >> 2) + 4 * h2);
            #pragma unroll
            for (int nt = 0; nt < 4; nt++)
                #pragma unroll
                for (int r = 0; r < 16; r++) oacc[nt][r] *= scr[r];
            m_r = mn;
        }
        float sum = 0.f;
        #pragma unroll
        for (int r = 0; r < 16; r++) {
            s0[r] = __expf(s0[r] - m_r); sum += s0[r];
            s1[r] = __expf(s1[r] - m_r); sum += s1[r];
        }
        sum += __shfl_xor(sum, 32);
        l_r += sum;
        unsigned ow0[8], ow1[8];
        #pragma unroll
        for (int a = 0; a < 4; a++) {
            ow0[a * 2 + 0] = cvtpk(s0[4 * a + 0], s0[4 * a + 1]);
            ow0[a * 2 + 1] = cvtpk(s0[4 * a + 2], s0[4 * a + 3]);
            ow1[a * 2 + 0] = cvtpk(s1[4 * a + 0], s1[4 * a + 1]);
            ow1[a * 2 + 1] = cvtpk(s1[4 * a + 2], s1[4 * a + 3]);
        }
        unsigned pw0[8], pw1[8];
        #pragma unroll
        for (int i = 0; i < 8; i++) {
            pw0[i] = __shfl_xor((int)ow0[i], 32);
            pw1[i] = __shfl_xor((int)ow1[i], 32);
        }
        bf16x8 pf[4];
        const bool lo = (h2 == 0);
        #pragma unroll
        for (int sub = 0; sub < 2; sub++) {
            int b0 = 2 * sub, b1 = 2 * sub + 1;
            u32x4 t0, t1;
            t0.x = lo ? ow0[b0 * 2 + 0] : pw0[b1 * 2 + 0];
            t0.y = lo ? ow0[b0 * 2 + 1] : pw0[b1 * 2 + 1];
            t0.z = lo ? pw0[b0 * 2 + 0] : ow0[b1 * 2 + 0];
            t0.w = lo ? pw0[b0 * 2 + 1] : ow0[b1 * 2 + 1];
            pf[sub] = __builtin_bit_cast(bf16x8, t0);
            t1.x = lo ? ow1[b0 * 2 + 0] : pw1[b1 * 2 + 0];
            t1.y = lo ? ow1[b0 * 2 + 1] : pw1[b1 * 2 + 1];
            t1.z = lo ? pw1[b0 * 2 + 0] : ow1[b1 * 2 + 0];
            t1.w = lo ? pw1[b0 * 2 + 1] : ow1[b1 * 2 + 1];
            pf[2 + sub] = __builtin_bit_cast(bf16x8, t1);
        }
        #pragma unroll
        for (int nt = 0; nt < 4; nt++) {
            int vr2 = nt * 32 + q31;
            #pragma unroll
            for (int kt16 = 0; kt16 < 4; kt16++) {
                int vc2 = (kt16 * 2 + h2) ^ (vr2 & 7);
                bf16x8 vf = *(const bf16x8*)&Vs[vr2 * 64 + vc2 * 8];
                oacc[nt] = __builtin_amdgcn_mfma_f32_32x32x16_bf16(pf[kt16], vf, oacc[nt], 0, 0, 0);
            }
        }
    }
    float inv = 1.0f / l_r;
    float invr[16];
    #pragma unroll
    for (int r = 0; r < 16; r++) invr[r] = __shfl(inv, (r & 3) + 8 * (r >> 2) + 4 * h2);
    #pragma unroll
    for (int nt = 0; nt < 4; nt++)
        #pragma unroll
        for (int r = 0; r < 16; r++) {
            int qg = q0w + (r & 3) + 8 * (r >> 2) + 4 * h2;
            O[(size_t)qg * HDIM + h * DHEAD + nt * 32 + q31] = f2bf(oacc[nt][r] * invr[r]);
        }
}

extern "C" void kernel_launch(void* const* d_in, const int* in_sizes, int n_in,
                              void* d_out, int out_size, void* d_ws, size_t ws_size,
                              hipStream_t stream) {
    const float* hs  = (const float*)d_in[0];
    const float* lnw = (const float*)d_in[1];
    const float* lnb = (const float*)d_in[2];
    const float* wq  = (const float*)d_in[3];
    const float* wk  = (const float*)d_in[4];
    const float* wv  = (const float*)d_in[5];
    const float* wo  = (const float*)d_in[6];
    float* out = (float*)d_out;

    char* ws = (char*)d_ws;
    size_t off = 0;
    auto alloc = [&](size_t bytes) {
        void* p = ws + off;
        off += (bytes + 255) & ~(size_t)255;
        return p;
    };
    unsigned short* xb   = (unsigned short*)alloc((size_t)SEQ * HDIM * 2);
    // wqT/wkT/wvT contiguous -> fused [6144][4096] B matrix
    unsigned short* wqT  = (unsigned short*)alloc((size_t)HDIM * (NQH * DHEAD) * 2);
    unsigned short* wkT  = (unsigned short*)alloc((size_t)HDIM * (NKVH * DHEAD) * 2);
    unsigned short* wvT  = (unsigned short*)alloc((size_t)HDIM * (NKVH * DHEAD) * 2);
    unsigned short* woT  = (unsigned short*)alloc((size_t)(NQH * DHEAD) * HDIM * 2);
    unsigned short* qkvb = (unsigned short*)alloc((size_t)SEQ * QKVN * 2);
    unsigned short* qbuf = (unsigned short*)alloc((size_t)NQH * SEQ * DHEAD * 2);
    unsigned short* kbuf = (unsigned short*)alloc((size_t)NKVH * SEQ * DHEAD * 2);
    unsigned short* vbt  = (unsigned short*)alloc((size_t)NKVH * DHEAD * SEQ * 2);
    unsigned short* attnb = qkvb;  // overlay: qkv consumed by rope/transpose_v before attention

    dim3 tb(32, 8);
    // all 4 weight transposes in one launch (z: wq, wk, wv, wo)
    transpose_convert_all<<<dim3(4096 / 32, 4096 / 64, 4), tb, 0, stream>>>(
        wq, wk, wv, wo, wqT, wkT, wvT, woT);

    layernorm_kernel<<<SEQ, 256, 0, stream>>>(hs, lnw, lnb, xb);

    // fused QKV projection (bf16 out): BM=256 x BN=192 -> grid 8 x 32 = 256 (full chip)
    gemm11<<<(2048 / 256) * (QKVN / 192), 512, 0, stream>>>(
        xb, wqT, qkvb, QKVN, 4096, 4096, QKVN / 192, 1);

    rope_convert<<<dim3(SEQ, NQH + NKVH), 64, 0, stream>>>(qkvb, qbuf, kbuf);
    transpose_v<<<dim3(SEQ / 32, DHEAD / 32, NKVH), tb, 0, stream>>>(qkvb, vbt);

    // swapped-QK attention: grid = 32 heads x 16 q-slabs (128 rows each), 4 warps/block
    attention_kernel<<<NQH * 16, 256, 0, stream>>>(qbuf, kbuf, vbt, attnb);

    // O-proj: full K=4096, grid 8 x 32 = 256 blocks exactly
    gemm8n<<<(2048 / 256) * (4096 / 128), 512, 0, stream>>>(
        attnb, woT, out, 4096, 4096, 4096, 4096 / 128);
}

// Round 20
// 299.473 us; speedup vs baseline: 1.0806x; 1.0229x over previous
//
#include <hip/hip_runtime.h>
#include <hip/hip_bf16.h>

#define HDIM 4096
#define DHEAD 128
#define NQH 32
#define NKVH 8
#define SEQ 2048
#define QKVN 6144  // fused N = 4096 + 1024 + 1024

typedef __bf16 bf16x8 __attribute__((ext_vector_type(8)));
typedef unsigned short ushort8 __attribute__((ext_vector_type(8)));
typedef float f32x4 __attribute__((ext_vector_type(4)));
typedef float f32x16 __attribute__((ext_vector_type(16)));
typedef unsigned int u32x2 __attribute__((ext_vector_type(2)));
typedef unsigned int u32x4 __attribute__((ext_vector_type(4)));

// wait until <= N vector-memory ops outstanding (lgkm/exp not waited)
#define WAIT_VM(N) __builtin_amdgcn_s_waitcnt(0xF70 | (N))

__device__ inline unsigned short f2bf(float f) {
    unsigned u = __float_as_uint(f);
    u += 0x7fffu + ((u >> 16) & 1u);
    return (unsigned short)(u >> 16);
}

__device__ inline float bf2f(unsigned short u) {
    return __uint_as_float(((unsigned)u) << 16);
}

// pack two f32 -> {lo:bf16, hi:bf16} in one u32 (low word = first arg)
__device__ inline unsigned cvtpk(float lo, float hi) {
    unsigned r;
    asm("v_cvt_pk_bf16_f32 %0, %1, %2" : "=v"(r) : "v"(lo), "v"(hi));
    return r;
}

__device__ inline void gload16(const void* g, void* l) {
    __builtin_amdgcn_global_load_lds(
        (const __attribute__((address_space(1))) unsigned int*)g,
        (__attribute__((address_space(3))) unsigned int*)l, 16, 0, 0);
}

// ------- merged weight transpose + fp32->bf16: 4 weights in one launch (z-indexed) -----
__global__ void transpose_convert_all(
    const float* __restrict__ wq, const float* __restrict__ wk,
    const float* __restrict__ wv, const float* __restrict__ wo,
    unsigned short* __restrict__ wqT, unsigned short* __restrict__ wkT,
    unsigned short* __restrict__ wvT, unsigned short* __restrict__ woT) {
    const int z = blockIdx.z;
    const float* in;
    unsigned short* out;
    int N;
    if (z == 0)      { in = wq; out = wqT; N = 4096; }
    else if (z == 1) { in = wk; out = wkT; N = 1024; }
    else if (z == 2) { in = wv; out = wvT; N = 1024; }
    else             { in = wo; out = woT; N = 4096; }
    const int n0 = blockIdx.x * 32, k0 = blockIdx.y * 64;
    if (n0 >= N) return;  // block-uniform exit (before any barrier)
    __shared__ float tile[64][33];
    const int tx = threadIdx.x, ty = threadIdx.y;  // 32 x 8
    #pragma unroll
    for (int r = 0; r < 8; r++)
        tile[ty + r * 8][tx] = in[(size_t)(k0 + ty + r * 8) * N + n0 + tx];
    __syncthreads();
    #pragma unroll
    for (int r = 0; r < 4; r++) {
        int n = ty + r * 8;
        unsigned v = (unsigned)f2bf(tile[tx * 2][n]) |
                     ((unsigned)f2bf(tile[tx * 2 + 1][n]) << 16);
        *(unsigned*)&out[(size_t)(n0 + n) * 4096 + k0 + tx * 2] = v;
    }
}

// ---------------- V transpose: bf16 qkv-fused row -> bf16 (NKVH, D, S) ----------------
__global__ void transpose_v(const unsigned short* __restrict__ qkvb,
                            unsigned short* __restrict__ vbt) {
    __shared__ unsigned short tile[32][34];
    const int s0 = blockIdx.x * 32, d0 = blockIdx.y * 32, hv = blockIdx.z;
    const int tx = threadIdx.x, ty = threadIdx.y;  // 32 x 8
    for (int r = 0; r < 32; r += 8)
        tile[ty + r][tx] = qkvb[(size_t)(s0 + ty + r) * QKVN + 5120 + hv * DHEAD + d0 + tx];
    __syncthreads();
    for (int r = 0; r < 32; r += 8)
        vbt[((size_t)hv * DHEAD + d0 + ty + r) * SEQ + s0 + tx] = tile[tx][ty + r];
}

// ---------------- LayerNorm: fp32 (S,H) -> bf16 (S,H); float4 loads (G13) --------------
__global__ __launch_bounds__(256) void layernorm_kernel(
    const float* __restrict__ hs, const float* __restrict__ w, const float* __restrict__ b,
    unsigned short* __restrict__ xb) {
    const int s = blockIdx.x;
    const float* row = hs + (size_t)s * HDIM;
    const int t = threadIdx.x;
    f32x4 v4[4];
    float sum = 0.f, sq = 0.f;
    #pragma unroll
    for (int j = 0; j < 4; j++) {
        v4[j] = *(const f32x4*)&row[j * 1024 + t * 4];
        #pragma unroll
        for (int e = 0; e < 4; e++) { float v = v4[j][e]; sum += v; sq += v * v; }
    }
    for (int off = 1; off < 64; off <<= 1) {
        sum += __shfl_xor(sum, off);
        sq  += __shfl_xor(sq, off);
    }
    __shared__ float ps[4], pq[4];
    if ((t & 63) == 0) { ps[t >> 6] = sum; pq[t >> 6] = sq; }
    __syncthreads();
    sum = ps[0] + ps[1] + ps[2] + ps[3];
    sq  = pq[0] + pq[1] + pq[2] + pq[3];
    const float mu = sum * (1.0f / HDIM);
    const float var = sq * (1.0f / HDIM) - mu * mu;
    const float rs = rsqrtf(var + 1e-5f);
    #pragma unroll
    for (int j = 0; j < 4; j++) {
        int i = j * 1024 + t * 4;
        f32x4 w4 = *(const f32x4*)&w[i];
        f32x4 b4 = *(const f32x4*)&b[i];
        float r0 = (v4[j][0] - mu) * rs * w4[0] + b4[0];
        float r1 = (v4[j][1] - mu) * rs * w4[1] + b4[1];
        float r2 = (v4[j][2] - mu) * rs * w4[2] + b4[2];
        float r3 = (v4[j][3] - mu) * rs * w4[3] + b4[3];
        u32x2 pk;
        pk.x = cvtpk(r0, r1);
        pk.y = cvtpk(r2, r3);
        *(u32x2*)&xb[(size_t)s * HDIM + i] = pk;
    }
}

// ------- gemm11 (QKV): BM=256, BN=192, BK=64 -> grid 8 x 32 = 256 blocks (full chip) ---
// r16 best config: counted-vmcnt single-gate schedule (NO barrier-pair phase heads —
// r7/r13/r18 all show those regress here).
__global__ __launch_bounds__(512, 1) void gemm11(
    const unsigned short* __restrict__ A, const unsigned short* __restrict__ Bt,
    void* __restrict__ Cout, int N, int lda, int Keff, int nbx, int cBf16) {
    __shared__ __align__(16) unsigned short Abuf[2 * 2 * 256 * 32];  // 64 KB
    __shared__ __align__(16) unsigned short Bbuf[2 * 192 * 64];      // 48 KB

    const int inner = blockIdx.x;
    const int cbx = nbx >> 3;
    const int xcd = inner & 7, k = inner >> 3;
    const int bx = xcd * cbx + (k % cbx);
    const int by = k / cbx;
    const int row0 = by * 256, col0 = bx * 192;

    const int t = threadIdx.x, lane = t & 63, w = t >> 6;
    const int wr = w >> 2, wc = w & 3;          // 2M x 4N wave grid
    const int r16 = lane & 15, kq = lane >> 4;

    const int srowA = t >> 2;
    const int scswA = (t & 3) ^ ((srowA >> 1) & 3);
    const unsigned short* aS = A + (size_t)(row0 + srowA) * lda + scswA * 8;
    const int srowB = t >> 3;
    const int scswB = (t & 7) ^ (srowB & 7);
    const unsigned short* bS = Bt + (size_t)(col0 + srowB) * lda + scswB * 8;
    const size_t a128 = 128 * (size_t)lda;
    const size_t b64 = 64 * (size_t)lda;
    const int wdst = w * 512;

    const int NT = Keff / 64;

#define SA11(bufi, kh, kt) {                                                        \
        const unsigned short* _g = aS + (size_t)(kt) * 64 + (kh) * 32;              \
        gload16(_g,        &Abuf[(bufi) * 16384 + (kh) * 8192 + wdst]);             \
        gload16(_g + a128, &Abuf[(bufi) * 16384 + (kh) * 8192 + 4096 + wdst]); }
#define SB11(bufi, kt) {                                                            \
        const unsigned short* _g = bS + (size_t)(kt) * 64;                          \
        gload16(_g,            &Bbuf[(bufi) * 12288 + wdst]);                       \
        gload16(_g + b64,      &Bbuf[(bufi) * 12288 + 4096 + wdst]);                \
        gload16(_g + 2 * b64,  &Bbuf[(bufi) * 12288 + 8192 + wdst]); }
#define RA11(dst, bufi, kh) { _Pragma("unroll") for (int i = 0; i < 8; i++) {       \
        int ar = wr * 128 + i * 16 + r16;                                           \
        dst[i] = *(const bf16x8*)&Abuf[(bufi) * 16384 + (kh) * 8192 + ar * 32 +     \
                 (kq ^ ((ar >> 1) & 3)) * 8]; } }
#define RB11(dst, bufi, kh) { _Pragma("unroll") for (int j = 0; j < 3; j++) {       \
        int br = wc * 48 + j * 16 + r16;                                            \
        dst[j] = *(const bf16x8*)&Bbuf[(bufi) * 12288 + br * 64 +                   \
                 ((((kh) * 4) + kq) ^ (br & 7)) * 8]; } }
#define MM11(av, bv) { __builtin_amdgcn_s_setprio(1);                               \
        _Pragma("unroll") for (int i = 0; i < 8; i++)                               \
            _Pragma("unroll") for (int j = 0; j < 3; j++)                           \
                acc[i][j] = __builtin_amdgcn_mfma_f32_16x16x32_bf16(                \
                    av[i], bv[j], acc[i][j], 0, 0, 0);                              \
        __builtin_amdgcn_s_setprio(0); }

    // prologue: stage tile 0 fully; leave A-kh1(0) in flight
    SA11(0, 0, 0);
    SB11(0, 0);
    SA11(0, 1, 0);
    WAIT_VM(2);
    __builtin_amdgcn_s_barrier();

    f32x4 acc[8][3] = {};
    for (int kt = 0; kt < NT; ++kt) {
        const int cur = kt & 1, nxt = cur ^ 1;
        const bool pf = (kt + 1 < NT);
        bf16x8 av[8], bv[3];
        // ph0: kh0
        RA11(av, cur, 0);
        RB11(bv, cur, 0);
        if (pf) SA11(nxt, 0, kt + 1);
        MM11(av, bv);
        if (pf) WAIT_VM(2); else WAIT_VM(0);   // force A-kh1(kt) landed
        __builtin_amdgcn_s_barrier();
        // ph1: kh1
        RA11(av, cur, 1);
        RB11(bv, cur, 1);
        if (pf) { SB11(nxt, kt + 1); SA11(nxt, 1, kt + 1); }
        MM11(av, bv);
        if (pf) {
            WAIT_VM(2);                        // force A-kh0(kt+1)+B(kt+1); kh1 in flight
            __builtin_amdgcn_s_barrier();
        }
    }

    if (cBf16) {
        unsigned short* C = (unsigned short*)Cout;
        #pragma unroll
        for (int i = 0; i < 8; i++)
            #pragma unroll
            for (int j = 0; j < 3; j++)
                #pragma unroll
                for (int r = 0; r < 4; r++) {
                    int row = row0 + wr * 128 + i * 16 + kq * 4 + r;
                    int col = col0 + wc * 48 + j * 16 + r16;
                    C[(size_t)row * N + col] = f2bf(acc[i][j][r]);
                }
    } else {
        float* C = (float*)Cout;
        #pragma unroll
        for (int i = 0; i < 8; i++)
            #pragma unroll
            for (int j = 0; j < 3; j++)
                #pragma unroll
                for (int r = 0; r < 4; r++) {
                    int row = row0 + wr * 128 + i * 16 + kq * 4 + r;
                    int col = col0 + wc * 48 + j * 16 + r16;
                    C[(size_t)row * N + col] = acc[i][j][r];
                }
    }
#undef SA11
#undef SB11
#undef RA11
#undef RB11
#undef MM11
}

// ---------------- O-proj GEMM: BM=256, BN=128, BK=64, 3-buf counted vmcnt (r12/r14) ----
__global__ __launch_bounds__(512, 2) void gemm8n(
    const unsigned short* __restrict__ A, const unsigned short* __restrict__ Bt,
    float* __restrict__ C, int N, int lda, int Keff, int nbx) {
    __shared__ __align__(16) unsigned short Abuf[3][256 * 64];  // 96 KB
    __shared__ __align__(16) unsigned short Bbuf[3][128 * 64];  // 48 KB

    const int inner = blockIdx.x;
    const int cbx = nbx >> 3;
    const int xcd = inner & 7, kk = inner >> 3;
    const int bx = xcd * cbx + (kk % cbx);
    const int by = kk / cbx;
    const int row0 = by * 256, col0 = bx * 128;

    const int t = threadIdx.x, lane = t & 63, w = t >> 6;
    const int wr = w >> 1, wc = w & 1;          // 4M x 2N wave grid
    const int r16 = lane & 15, kq = lane >> 4;

    const int srow = t >> 3;                    // 0..63
    const int scsw = (t & 7) ^ (srow & 7);
    const unsigned short* aStage = A  + (size_t)(row0 + srow) * lda + scsw * 8;
    const unsigned short* bStage = Bt + (size_t)(col0 + srow) * lda + scsw * 8;
    const size_t rstep = 64 * (size_t)lda;

    const int NT = Keff / 64;

#define NSTG_H0(bufi, kt) {                                                     \
        gload16(aStage + (size_t)(kt) * 64,             &Abuf[bufi][0 * 4096 + w * 512]); \
        gload16(aStage + (size_t)(kt) * 64 + rstep,     &Abuf[bufi][1 * 4096 + w * 512]); \
        gload16(bStage + (size_t)(kt) * 64,             &Bbuf[bufi][0 * 4096 + w * 512]); }
#define NSTG_H1(bufi, kt) {                                                     \
        gload16(aStage + (size_t)(kt) * 64 + 2 * rstep, &Abuf[bufi][2 * 4096 + w * 512]); \
        gload16(aStage + (size_t)(kt) * 64 + 3 * rstep, &Abuf[bufi][3 * 4096 + w * 512]); \
        gload16(bStage + (size_t)(kt) * 64 + rstep,     &Bbuf[bufi][1 * 4096 + w * 512]); }

#define NLDA(dst, bufi, kh) { _Pragma("unroll") for (int i = 0; i < 4; i++) {   \
        int ar = wr * 64 + i * 16 + r16;                                        \
        dst[i] = *(const bf16x8*)&Abuf[bufi][ar * 64 + (((kh) * 4 + kq) ^ (ar & 7)) * 8]; } }
#define NLDB(dst, bufi, kh) { _Pragma("unroll") for (int j = 0; j < 4; j++) {   \
        int br = wc * 64 + j * 16 + r16;                                        \
        dst[j] = *(const bf16x8*)&Bbuf[bufi][br * 64 + (((kh) * 4 + kq) ^ (br & 7)) * 8]; } }

#define MMN(av, bv) {                                                           \
        __builtin_amdgcn_s_setprio(1);                                          \
        _Pragma("unroll") for (int i = 0; i < 4; i++)                           \
            _Pragma("unroll") for (int j = 0; j < 4; j++)                       \
                acc[i][j] = __builtin_amdgcn_mfma_f32_16x16x32_bf16(            \
                    av[i], bv[j], acc[i][j], 0, 0, 0);                          \
        __builtin_amdgcn_s_setprio(0); }

    NSTG_H0(0, 0); NSTG_H1(0, 0);
    NSTG_H0(1, 1); NSTG_H1(1, 1);
    WAIT_VM(6);
    __builtin_amdgcn_s_barrier();

    f32x4 acc[4][4] = {};
    for (int kt = 0; kt < NT; ++kt) {
        const int cur = kt % 3, nx2 = (kt + 2) % 3;
        const bool pf = (kt + 2) < NT;
        bf16x8 av[4], bv[4];
        NLDA(av, cur, 0);
        NLDB(bv, cur, 0);
        if (pf) NSTG_H0(nx2, kt + 2);
        MMN(av, bv);
        NLDA(av, cur, 1);
        NLDB(bv, cur, 1);
        if (pf) NSTG_H1(nx2, kt + 2);
        MMN(av, bv);
        if (kt + 1 < NT) {
            if (pf) WAIT_VM(6); else WAIT_VM(0);
            __builtin_amdgcn_s_barrier();
        }
    }

    #pragma unroll
    for (int i = 0; i < 4; i++)
        #pragma unroll
        for (int j = 0; j < 4; j++)
            #pragma unroll
            for (int r = 0; r < 4; r++) {
                int row = row0 + wr * 64 + i * 16 + kq * 4 + r;
                int col = col0 + wc * 64 + j * 16 + r16;
                C[(size_t)row * N + col] = acc[i][j][r];
            }
#undef NSTG_H0
#undef NSTG_H1
#undef NLDA
#undef NLDB
#undef MMN
}

// ---------------- RoPE: vectorized ushort2 loads/stores + shfl pair exchange -----------
// 256 thr = 4 waves, one head per wave (grid SEQ x 10). Lane l loads elements 2l,2l+1
// (4B); partner half obtained via __shfl(x, l^32); freq index = 2*(l&31) for both
// halves (cos/sin identical for d and d+64). Output also lands at elements 2l (4B).
__global__ __launch_bounds__(256) void rope_convert(
    const unsigned short* __restrict__ qkvb,
    unsigned short* __restrict__ qb, unsigned short* __restrict__ kb) {
    const int s = blockIdx.x;
    const int g = threadIdx.x >> 6, l = threadIdx.x & 63;
    const int head = blockIdx.y * 4 + g;  // 0..39
    const int dl = l & 31;
    const float NLOG = -0.14391156831212787f;  // -ln(10000)/64
    float f0 = (float)s * __expf((float)(2 * dl) * NLOG);
    float f1 = (float)s * __expf((float)(2 * dl + 1) * NLOG);
    float sn0, c0, sn1, c1;
    __sincosf(f0, &sn0, &c0);
    __sincosf(f1, &sn1, &c1);
    const unsigned short* src;
    unsigned short* dst;
    float scale;
    if (head < NQH) {
        src = qkvb + (size_t)s * QKVN + head * DHEAD;
        dst = qb + ((size_t)head * SEQ + s) * DHEAD;
        scale = 0.08838834764831845f;  // 1/sqrt(128)
    } else {
        int hk = head - NQH;
        src = qkvb + (size_t)s * QKVN + 4096 + hk * DHEAD;
        dst = kb + ((size_t)hk * SEQ + s) * DHEAD;
        scale = 1.0f;
    }
    unsigned pv = *(const unsigned*)&src[2 * l];
    float a0 = bf2f((unsigned short)(pv & 0xffffu));
    float a1 = bf2f((unsigned short)(pv >> 16));
    float p0 = __shfl(a0, l ^ 32);
    float p1 = __shfl(a1, l ^ 32);
    float o0, o1;
    if (l < 32) { o0 = (a0 * c0 - p0 * sn0) * scale; o1 = (a1 * c1 - p1 * sn1) * scale; }
    else        { o0 = (a0 * c0 + p0 * sn0) * scale; o1 = (a1 * c1 + p1 * sn1) * scale; }
    *(unsigned*)&dst[2 * l] = cvtpk(o0, o1);
}

// ---------------- Flash attention: swapped QK^T + in-register softmax (32x32 MFMA) -----
__global__ __launch_bounds__(256, 2) void attention_kernel(
    const unsigned short* __restrict__ Q, const unsigned short* __restrict__ K,
    const unsigned short* __restrict__ Vt, unsigned short* __restrict__ O) {
    __shared__ __align__(16) unsigned short Ks[64 * 128];  // [kcol][d], swizzled
    __shared__ __align__(16) unsigned short Vs[128 * 64];  // [d][k],   swizzled
    const int h = blockIdx.x & 31;
    const int p = 15 - (blockIdx.x >> 5);   // LPT: largest slabs first
    const int t = threadIdx.x, lane = t & 63, w = t >> 6;
    const int q31 = lane & 31, h2 = lane >> 5;
    const int q0w = p * 128 + w * 32;
    const int kbw = 2 * p + (w >> 1);       // this warp's diagonal kb
    const int kbmax = 2 * p + 1;            // block's last kb
    const int hkv = h >> 2;

    bf16x8 qf[8];
    {
        const unsigned short* qrow = Q + ((size_t)h * SEQ + q0w + q31) * DHEAD + h2 * 8;
        #pragma unroll
        for (int ds = 0; ds < 8; ds++) qf[ds] = *(const bf16x8*)&qrow[ds * 16];
    }

    f32x16 oacc[4] = {};
    float m_r = -1e30f, l_r = 0.f;

    const unsigned short* Kg = K + (size_t)hkv * SEQ * DHEAD;
    const unsigned short* Vg = Vt + (size_t)hkv * DHEAD * SEQ;

    const int krow = t >> 4, kch = t & 15;
    const int vrow = t >> 3, vch = t & 7;
    ushort8 kreg[4], vreg[4];
    #pragma unroll
    for (int pp = 0; pp < 4; pp++) {
        kreg[pp] = *(const ushort8*)&Kg[(size_t)(pp * 16 + krow) * DHEAD + kch * 8];
        vreg[pp] = *(const ushort8*)&Vg[(size_t)(pp * 32 + vrow) * SEQ + vch * 8];
    }

    for (int kb = 0; kb <= kbmax; ++kb) {
        __syncthreads();
        #pragma unroll
        for (int pp = 0; pp < 4; pp++) {
            int row = pp * 16 + krow;
            *(ushort8*)&Ks[row * 128 + ((kch ^ (row & 7)) * 8)] = kreg[pp];
            int vr = pp * 32 + vrow;
            *(ushort8*)&Vs[vr * 64 + ((vch ^ (vr & 7)) * 8)] = vreg[pp];
        }
        if (kb < kbmax) {
            #pragma unroll
            for (int pp = 0; pp < 4; pp++) {
                kreg[pp] = *(const ushort8*)&Kg[(size_t)((kb + 1) * 64 + pp * 16 + krow) * DHEAD + kch * 8];
                vreg[pp] = *(const ushort8*)&Vg[(size_t)(pp * 32 + vrow) * SEQ + (kb + 1) * 64 + vch * 8];
            }
        }
        __syncthreads();
        if (kb > kbw) continue;

        f32x16 s0 = {}, s1 = {};
        #pragma unroll
        for (int ds = 0; ds < 8; ds++) {
            int r0 = q31;
            int c0 = (ds * 2 + h2) ^ (r0 & 7);
            bf16x8 kf0 = *(const bf16x8*)&Ks[r0 * 128 + c0 * 8];
            s0 = __builtin_amdgcn_mfma_f32_32x32x16_bf16(kf0, qf[ds], s0, 0, 0, 0);
            int r1 = 32 + q31;
            int c1 = (ds * 2 + h2) ^ (r1 & 7);
            bf16x8 kf1 = *(const bf16x8*)&Ks[r1 * 128 + c1 * 8];
            s1 = __builtin_amdgcn_mfma_f32_32x32x16_bf16(kf1, qf[ds], s1, 0, 0, 0);
        }
        if (kb == kbw) {
            const int qg = q0w + q31;
            #pragma unroll
            for (int r = 0; r < 16; r++) {
                int kpos = (r & 3) + 8 * (r >> 2) + 4 * h2;
                s0[r] = (kb * 64 + kpos > qg) ? -1e30f : s0[r];
                s1[r] = (kb * 64 + 32 + kpos > qg) ? -1e30f : s1[r];
            }
        }
        float pm = -1e30f;
        #pragma unroll
        for (int r = 0; r < 16; r++) pm = fmaxf(pm, fmaxf(s0[r], s1[r]));
        pm = fmaxf(pm, __shfl_xor(pm, 32));
        bool grow = pm > m_r + 8.f;
        if (__any(grow)) {
            float mn = fmaxf(m_r, pm);
            float sc = __expf(m_r - mn);
            l_r *= sc;
            float scr[16];
            #pragma unroll
            for (int r = 0; r < 16; r++) scr[r] = __shfl(sc, (r & 3) + 8 * (r >> 2) + 4 * h2);
            #pragma unroll
            for (int nt = 0; nt < 4; nt++)
                #pragma unroll
                for (int r = 0; r < 16; r++) oacc[nt][r] *= scr[r];
            m_r = mn;
        }
        float sum = 0.f;
        #pragma unroll
        for (int r = 0; r < 16; r++) {
            s0[r] = __expf(s0[r] - m_r); sum += s0[r];
            s1[r] = __expf(s1[r] - m_r); sum += s1[r];
        }
        sum += __shfl_xor(sum, 32);
        l_r += sum;
        unsigned ow0[8], ow1[8];
        #pragma unroll
        for (int a = 0; a < 4; a++) {
            ow0[a * 2 + 0] = cvtpk(s0[4 * a + 0], s0[4 * a + 1]);
            ow0[a * 2 + 1] = cvtpk(s0[4 * a + 2], s0[4 * a + 3]);
            ow1[a * 2 + 0] = cvtpk(s1[4 * a + 0], s1[4 * a + 1]);
            ow1[a * 2 + 1] = cvtpk(s1[4 * a + 2], s1[4 * a + 3]);
        }
        unsigned pw0[8], pw1[8];
        #pragma unroll
        for (int i = 0; i < 8; i++) {
            pw0[i] = __shfl_xor((int)ow0[i], 32);
            pw1[i] = __shfl_xor((int)ow1[i], 32);
        }
        bf16x8 pf[4];
        const bool lo = (h2 == 0);
        #pragma unroll
        for (int sub = 0; sub < 2; sub++) {
            int b0 = 2 * sub, b1 = 2 * sub + 1;
            u32x4 t0, t1;
            t0.x = lo ? ow0[b0 * 2 + 0] : pw0[b1 * 2 + 0];
            t0.y = lo ? ow0[b0 * 2 + 1] : pw0[b1 * 2 + 1];
            t0.z = lo ? pw0[b0 * 2 + 0] : ow0[b1 * 2 + 0];
            t0.w = lo ? pw0[b0 * 2 + 1] : ow0[b1 * 2 + 1];
            pf[sub] = __builtin_bit_cast(bf16x8, t0);
            t1.x = lo ? ow1[b0 * 2 + 0] : pw1[b1 * 2 + 0];
            t1.y = lo ? ow1[b0 * 2 + 1] : pw1[b1 * 2 + 1];
            t1.z = lo ? pw1[b0 * 2 + 0] : ow1[b1 * 2 + 0];
            t1.w = lo ? pw1[b0 * 2 + 1] : ow1[b1 * 2 + 1];
            pf[2 + sub] = __builtin_bit_cast(bf16x8, t1);
        }
        #pragma unroll
        for (int nt = 0; nt < 4; nt++) {
            int vr2 = nt * 32 + q31;
            #pragma unroll
            for (int kt16 = 0; kt16 < 4; kt16++) {
                int vc2 = (kt16 * 2 + h2) ^ (vr2 & 7);
                bf16x8 vf = *(const bf16x8*)&Vs[vr2 * 64 + vc2 * 8];
                oacc[nt] = __builtin_amdgcn_mfma_f32_32x32x16_bf16(pf[kt16], vf, oacc[nt], 0, 0, 0);
            }
        }
    }
    float inv = 1.0f / l_r;
    float invr[16];
    #pragma unroll
    for (int r = 0; r < 16; r++) invr[r] = __shfl(inv, (r & 3) + 8 * (r >> 2) + 4 * h2);
    #pragma unroll
    for (int nt = 0; nt < 4; nt++)
        #pragma unroll
        for (int r = 0; r < 16; r++) {
            int qg = q0w + (r & 3) + 8 * (r >> 2) + 4 * h2;
            O[(size_t)qg * HDIM + h * DHEAD + nt * 32 + q31] = f2bf(oacc[nt][r] * invr[r]);
        }
}

extern "C" void kernel_launch(void* const* d_in, const int* in_sizes, int n_in,
                              void* d_out, int out_size, void* d_ws, size_t ws_size,
                              hipStream_t stream) {
    const float* hs  = (const float*)d_in[0];
    const float* lnw = (const float*)d_in[1];
    const float* lnb = (const float*)d_in[2];
    const float* wq  = (const float*)d_in[3];
    const float* wk  = (const float*)d_in[4];
    const float* wv  = (const float*)d_in[5];
    const float* wo  = (const float*)d_in[6];
    float* out = (float*)d_out;

    char* ws = (char*)d_ws;
    size_t off = 0;
    auto alloc = [&](size_t bytes) {
        void* p = ws + off;
        off += (bytes + 255) & ~(size_t)255;
        return p;
    };
    unsigned short* xb   = (unsigned short*)alloc((size_t)SEQ * HDIM * 2);
    // wqT/wkT/wvT contiguous -> fused [6144][4096] B matrix
    unsigned short* wqT  = (unsigned short*)alloc((size_t)HDIM * (NQH * DHEAD) * 2);
    unsigned short* wkT  = (unsigned short*)alloc((size_t)HDIM * (NKVH * DHEAD) * 2);
    unsigned short* wvT  = (unsigned short*)alloc((size_t)HDIM * (NKVH * DHEAD) * 2);
    unsigned short* woT  = (unsigned short*)alloc((size_t)(NQH * DHEAD) * HDIM * 2);
    unsigned short* qkvb = (unsigned short*)alloc((size_t)SEQ * QKVN * 2);
    unsigned short* qbuf = (unsigned short*)alloc((size_t)NQH * SEQ * DHEAD * 2);
    unsigned short* kbuf = (unsigned short*)alloc((size_t)NKVH * SEQ * DHEAD * 2);
    unsigned short* vbt  = (unsigned short*)alloc((size_t)NKVH * DHEAD * SEQ * 2);
    unsigned short* attnb = qkvb;  // overlay: qkv consumed by rope/transpose_v before attention

    dim3 tb(32, 8);
    // all 4 weight transposes in one launch (z: wq, wk, wv, wo)
    transpose_convert_all<<<dim3(4096 / 32, 4096 / 64, 4), tb, 0, stream>>>(
        wq, wk, wv, wo, wqT, wkT, wvT, woT);

    layernorm_kernel<<<SEQ, 256, 0, stream>>>(hs, lnw, lnb, xb);

    // fused QKV projection (bf16 out): BM=256 x BN=192 -> grid 8 x 32 = 256 (full chip)
    gemm11<<<(2048 / 256) * (QKVN / 192), 512, 0, stream>>>(
        xb, wqT, qkvb, QKVN, 4096, 4096, QKVN / 192, 1);

    // RoPE (q,k): 256-thr blocks, 4 heads/block, vectorized ushort2 path
    rope_convert<<<dim3(SEQ, (NQH + NKVH) / 4), 256, 0, stream>>>(qkvb, qbuf, kbuf);
    transpose_v<<<dim3(SEQ / 32, DHEAD / 32, NKVH), tb, 0, stream>>>(qkvb, vbt);

    // swapped-QK attention: grid = 32 heads x 16 q-slabs (128 rows each), 4 warps/block
    attention_kernel<<<NQH * 16, 256, 0, stream>>>(qbuf, kbuf, vbt, attnb);

    // O-proj: full K=4096, grid 8 x 32 = 256 blocks exactly
    gemm8n<<<(2048 / 256) * (4096 / 128), 512, 0, stream>>>(
        attnb, woT, out, 4096, 4096, 4096, 4096 / 128);
}